// Round 2
// baseline (167.189 us; speedup 1.0000x reference)
//
#include <hip/hip_runtime.h>

// Causal MHA, B=128 T=256 C=384 H=6 d=64, fp32 in/out.
// prep: X->bf16; W->W^T bf16 via LDS tile transpose (Wq pre-scaled by 1/sqrt(C)*log2e).
// fused: one block per (b,h), 1024 thr = 16 waves (4/SIMD for latency hiding).
//   Phase A: QKV projection [256 tok x 192 n'], BK=64, 2-phase pipeline:
//            read frags -> barrier -> issue stage(kt+1) -> MFMA -> vmcnt(0)+barrier.
//   Epilogue: acc -> LDS Q-rows / K-rows / V^T, XOR bank-swizzled.
//   Phase B: flash attention from LDS, one 16-row q-group per wave; Latin-square
//            group map balances causal visits per SIMD; barrier-free.

typedef unsigned short u16;
typedef float f32x4 __attribute__((ext_vector_type(4)));
typedef short s16x8 __attribute__((ext_vector_type(8)));
typedef u16 u16x4 __attribute__((ext_vector_type(4)));

static constexpr int BB = 128;
static constexpr int TT = 256;
static constexpr int CC = 384;
static constexpr int HH = 6;
static constexpr int DD = 64;
static constexpr int MM = BB * TT;  // 32768

// ws layout (u16): WT3 [1152][384] | Xbf [M][384]
static constexpr size_t WTOFF = 0;
static constexpr size_t XOFF  = (size_t)3 * CC * CC;

// (1/sqrt(384)) * log2(e): folded into Wq so attn logits are already base-2
static constexpr float CSC = 0.07362242194579907f;

__device__ __forceinline__ u16 f2bf(float f) {
  unsigned u = __float_as_uint(f);
  u += 0x7fffu + ((u >> 16) & 1u);   // RTN-even
  return (u16)(u >> 16);
}

// async global->LDS, 16 B/lane; LDS dest = wave-uniform base + lane*16 (m104)
__device__ __forceinline__ void g2l16(const u16* g, u16* l) {
  __builtin_amdgcn_global_load_lds(
      (const __attribute__((address_space(1))) u16*)g,
      (__attribute__((address_space(3))) u16*)l, 16, 0, 0);
}

// ---------- prep: X fp32->bf16 (blocks 0..6143) + W^T via LDS transpose ----------
__global__ void prep(const float* __restrict__ X, const float* __restrict__ Wq,
                     const float* __restrict__ Wk, const float* __restrict__ Wv,
                     u16* __restrict__ ws) {
  int bx = blockIdx.x;
  if (bx < 6144) {
    size_t i = (size_t)(bx * 256 + threadIdx.x) * 8;
    f32x4 a0 = *(const f32x4*)(X + i);
    f32x4 a1 = *(const f32x4*)(X + i + 4);
    s16x8 ab;
#pragma unroll
    for (int j = 0; j < 4; ++j) { ab[j] = (short)f2bf(a0[j]); ab[4 + j] = (short)f2bf(a1[j]); }
    *(s16x8*)(ws + XOFF + i) = ab;
  } else {
    // 108 transpose blocks: z (3) x 6x6 tiles of 64x64
    __shared__ u16 Lt[64][66];
    int j = bx - 6144;
    int z = j / 36, t = j % 36, ti = t / 6, tj = t % 6;
    const float* W = (z == 0) ? Wq : (z == 1) ? Wk : Wv;
    const float sc = (z == 0) ? CSC : 1.0f;
    u16* WT = ws + WTOFF + (size_t)z * CC * CC;
    const int rl = threadIdx.x >> 4;
    const int cl = (threadIdx.x & 15) * 4;
#pragma unroll
    for (int it = 0; it < 4; ++it) {
      int r = it * 16 + rl;
      f32x4 v = *(const f32x4*)(W + (size_t)(ti * 64 + r) * CC + tj * 64 + cl);
#pragma unroll
      for (int q = 0; q < 4; ++q) Lt[r][cl + q] = f2bf(v[q] * sc);
    }
    __syncthreads();
#pragma unroll
    for (int it = 0; it < 4; ++it) {
      int n = it * 16 + rl;
      u16x4 o;
#pragma unroll
      for (int q = 0; q < 4; ++q) o[q] = Lt[cl + q][n];
      *(u16x4*)(WT + (size_t)(tj * 64 + n) * CC + ti * 64 + cl) = o;
    }
  }
}

// ---------- fused QKV projection + flash attention ----------
__global__ __launch_bounds__(1024, 4) void fused(const u16* __restrict__ ws,
                                                 float* __restrict__ out) {
  // XCD clustering: 6 heads of same b share ids congruent mod 8 -> same XCD L2
  const int bid = blockIdx.x;
  const int xc = bid & 7;
  const int g5 = bid >> 3;           // 0..95
  const int b = xc * 16 + g5 / 6;
  const int h = g5 % 6;

  __shared__ u16 R1[256][64];        // phase A: X chunk; phase B: Q rows (swizzled)
  __shared__ u16 R2[16][1152];       // phase A: W chunk (first 24KB); phase B: Ps
  __shared__ u16 Ks[256][64];        // K rows, XOR-swizzled
  __shared__ u16 VTs[64][256];       // V^T, XOR-swizzled

  const int tid = threadIdx.x;
  const int lane = tid & 63;
  const int w = tid >> 6;            // 0..15
  const int quad = lane >> 4;
  const int col = lane & 15;
  const int a = w >> 2;              // token quadrant
  const int bq = w & 3;              // n' slice
  const int wm = a * 64;
  const int wn = bq * 48;

  const u16* Xg = ws + XOFF + (size_t)b * TT * CC;   // [256][384]
  const u16* Wg = ws + WTOFF;                        // [1152][384]
  u16* Wst = &R2[0][0];                              // [192][64] staging view

  const int rl = lane >> 3;          // row within 8-row staging chunk
  const int gb = (lane & 7) ^ rl;    // swizzled 8-elem block for this lane

  // ---------------- Phase A: 256x192 projection, BK=64, pipelined ----------------
  auto stage = [&](int kt) {
    int r0 = w * 16;
    g2l16(Xg + (size_t)(r0 + rl) * CC + kt * 64 + gb * 8, &R1[r0][0]);
    g2l16(Xg + (size_t)(r0 + 8 + rl) * CC + kt * 64 + gb * 8, &R1[r0 + 8][0]);
    {
      int rr = w * 8 + rl;           // W chunk w: rows 0..127
      int z = rr >> 6, nn = rr & 63;
      g2l16(Wg + (size_t)(z * CC + h * DD + nn) * CC + kt * 64 + gb * 8,
            Wst + w * 512);
    }
    if (w < 8) {                     // W chunks 16..23: rows 128..191
      int c = w + 16;
      int rr = c * 8 + rl;
      int z = rr >> 6, nn = rr & 63;
      g2l16(Wg + (size_t)(z * CC + h * DD + nn) * CC + kt * 64 + gb * 8,
            Wst + c * 512);
    }
  };

  f32x4 acc[4][3] = {};

  stage(0);
  asm volatile("s_waitcnt vmcnt(0)" ::: "memory");
  __syncthreads();

  for (int kt = 0; kt < 6; ++kt) {
    s16x8 af[4][2], bf[3][2];
#pragma unroll
    for (int mt = 0; mt < 4; ++mt)
#pragma unroll
      for (int ks = 0; ks < 2; ++ks)
        af[mt][ks] = *(const s16x8*)(&R1[wm + mt * 16 + col]
                                        [(((ks * 4 + quad) ^ (col & 7)) * 8)]);
#pragma unroll
    for (int nt = 0; nt < 3; ++nt)
#pragma unroll
      for (int ks = 0; ks < 2; ++ks)
        bf[nt][ks] = *(const s16x8*)(Wst + (wn + nt * 16 + col) * 64 +
                                     (((ks * 4 + quad) ^ (col & 7)) * 8));

    __syncthreads();                 // (a) all waves done reading this chunk
    if (kt < 5) stage(kt + 1);       // loads fly under the MFMAs below

#pragma unroll
    for (int ks = 0; ks < 2; ++ks)
#pragma unroll
      for (int mt = 0; mt < 4; ++mt)
#pragma unroll
        for (int nt = 0; nt < 3; ++nt)
          acc[mt][nt] = __builtin_amdgcn_mfma_f32_16x16x32_bf16(
              af[mt][ks], bf[nt][ks], acc[mt][nt], 0, 0, 0);

    if (kt < 5) {
      asm volatile("s_waitcnt vmcnt(0)" ::: "memory");
      __syncthreads();               // (b) staged chunk visible to all
    }
  }
  // no barrier needed: last (a)-barrier ordered every wave's reads before any write

  // ---------------- Epilogue: acc -> Q(=R1)/K rows, V^T; XOR bank-swizzle ----------
#pragma unroll
  for (int mt = 0; mt < 4; ++mt) {
    int tokb = wm + mt * 16 + quad * 4;
#pragma unroll
    for (int nt = 0; nt < 3; ++nt) {
      int gn = wn + nt * 16 + col;           // 16-aligned slices: class uniform per nt
      if (gn < 128) {
        u16* dst = (gn < 64) ? &R1[0][0] : &Ks[0][0];
        int d = gn & 63;
#pragma unroll
        for (int r = 0; r < 4; ++r) {
          int tok = tokb + r;
          dst[tok * 64 + (d ^ ((tok & 7) << 3))] = f2bf(acc[mt][nt][r]);
        }
      } else {
        int d = gn - 128;
        uint2 pk;
        pk.x = (unsigned)f2bf(acc[mt][nt][0]) | ((unsigned)f2bf(acc[mt][nt][1]) << 16);
        pk.y = (unsigned)f2bf(acc[mt][nt][2]) | ((unsigned)f2bf(acc[mt][nt][3]) << 16);
        *(uint2*)((u16*)VTs + d * 256 + (tokb ^ ((d & 15) << 3))) = pk;
      }
    }
  }
  __syncthreads();

  // ---------------- Phase B: flash attention from LDS, barrier-free ----------------
  // Latin-square group map: balanced per SIMD for consecutive AND round-robin placement
  const int gcl = (a + bq) & 3;
  const int g = gcl * 4 + a;         // this wave's 16-row q-group, visits = gcl+1
  const int kthi = g >> 2;
  const int qq = (g & 3) * 16 + col; // q offset within diagonal 64-tile
  u16* Ps = &R2[w][col * 72];        // per-wave P^T round-trip [16 q][72 keys]

  s16x8 qf[2];
  {
    int q = g * 16 + col;
#pragma unroll
    for (int ks = 0; ks < 2; ++ks)
      qf[ks] = *(const s16x8*)(&R1[q][(((ks * 4 + quad) ^ (q & 7)) * 8)]);
  }

  f32x4 o[4] = {};
  float mst = -1.0e30f, lst = 0.0f;

  for (int kt = 0; kt <= kthi; ++kt) {
    s16x8 kf[4][2], vf[4][2];
#pragma unroll
    for (int nt = 0; nt < 4; ++nt)
#pragma unroll
      for (int ks = 0; ks < 2; ++ks) {
        int key = kt * 64 + nt * 16 + col;
        kf[nt][ks] = *(const s16x8*)(&Ks[key][(((ks * 4 + quad) ^ (col & 7)) * 8)]);
        int d = nt * 16 + col;
        vf[nt][ks] = *(const s16x8*)((const u16*)VTs + d * 256 +
                     ((kt * 64 + ks * 32 + quad * 8) ^ ((d & 15) << 3)));
      }

    // S^T tiles: row = key = nt*16+quad*4+r, col = q
    f32x4 s[4] = {};
#pragma unroll
    for (int ks = 0; ks < 2; ++ks)
#pragma unroll
      for (int nt = 0; nt < 4; ++nt)
        s[nt] = __builtin_amdgcn_mfma_f32_16x16x32_bf16(kf[nt][ks], qf[ks],
                                                        s[nt], 0, 0, 0);

    const bool diag = (kt == kthi);
    float rmax = -1.0e30f;
#pragma unroll
    for (int nt = 0; nt < 4; ++nt)
#pragma unroll
      for (int r = 0; r < 4; ++r) {
        float t = s[nt][r];
        if (diag && (nt * 16 + quad * 4 + r) > qq) t = -1.0e30f;
        s[nt][r] = t;
        rmax = fmaxf(rmax, t);
      }
    rmax = fmaxf(rmax, __shfl_xor(rmax, 16));
    rmax = fmaxf(rmax, __shfl_xor(rmax, 32));

    float mn = fmaxf(mst, rmax);
    float alpha = exp2f(mst - mn);
    mst = mn;

    float lsum = 0.0f;
    unsigned pk[4][2];
#pragma unroll
    for (int nt = 0; nt < 4; ++nt) {
      float p0 = exp2f(s[nt][0] - mn), p1 = exp2f(s[nt][1] - mn);
      float p2 = exp2f(s[nt][2] - mn), p3 = exp2f(s[nt][3] - mn);
      lsum += (p0 + p1) + (p2 + p3);
      pk[nt][0] = (unsigned)f2bf(p0) | ((unsigned)f2bf(p1) << 16);
      pk[nt][1] = (unsigned)f2bf(p2) | ((unsigned)f2bf(p3) << 16);
    }
    lst = lst * alpha + lsum;

    // P^T -> LDS first, then O-rescale overlaps the ds_write latency
    asm volatile("s_waitcnt lgkmcnt(0)" ::: "memory");  // WAR vs prev pf reads
#pragma unroll
    for (int nt = 0; nt < 4; ++nt)
      *(uint2*)(Ps + nt * 16 + quad * 4) = make_uint2(pk[nt][0], pk[nt][1]);

#pragma unroll
    for (int dt = 0; dt < 4; ++dt)
#pragma unroll
      for (int r = 0; r < 4; ++r) o[dt][r] *= alpha;

    asm volatile("s_waitcnt lgkmcnt(0)" ::: "memory");  // own-wave visibility
    s16x8 pf[2];
#pragma unroll
    for (int ks = 0; ks < 2; ++ks)
      pf[ks] = *(const s16x8*)(Ps + ks * 32 + quad * 8);

#pragma unroll
    for (int ks = 0; ks < 2; ++ks)
#pragma unroll
      for (int dt = 0; dt < 4; ++dt)
        o[dt] = __builtin_amdgcn_mfma_f32_16x16x32_bf16(vf[dt][ks], pf[ks],
                                                        o[dt], 0, 0, 0);
  }

  // epilogue: O^T row = d = dt*16+quad*4+r, col = q -> out[b,q,h*64+d]
  {
    float l = lst;
    l += __shfl_xor(l, 16);
    l += __shfl_xor(l, 32);
    float inv = 1.0f / l;
    int q = g * 16 + col;
#pragma unroll
    for (int dt = 0; dt < 4; ++dt) {
      f32x4 res;
#pragma unroll
      for (int r = 0; r < 4; ++r) res[r] = o[dt][r] * inv;
      *(f32x4*)(out + (size_t)(b * TT + q) * CC + h * DD + dt * 16 + quad * 4) = res;
    }
  }
}

extern "C" void kernel_launch(void* const* d_in, const int* in_sizes, int n_in,
                              void* d_out, int out_size, void* d_ws, size_t ws_size,
                              hipStream_t stream) {
  const float* x  = (const float*)d_in[0];
  const float* wq = (const float*)d_in[1];
  const float* wk = (const float*)d_in[2];
  const float* wv = (const float*)d_in[3];
  u16* ws  = (u16*)d_ws;
  float* out = (float*)d_out;

  prep<<<dim3(6144 + 108), 256, 0, stream>>>(x, wq, wk, wv, ws);
  fused<<<dim3(BB * HH), 1024, 0, stream>>>(ws, out);
}

// Round 3
// 154.880 us; speedup vs baseline: 1.0795x; 1.0795x over previous
//
#include <hip/hip_runtime.h>

// Causal MHA, B=128 T=256 C=384 H=6 d=64, fp32 in/out.
// prep: X->bf16; W->W^T bf16 via LDS tile transpose (Wq pre-scaled by 1/sqrt(C)*log2e).
// fused: one block per (b,h), 512 thr = 8 waves (regs pin occupancy at 2 waves/SIMD;
//        round-2's 4/SIMD attempt spilled: WRITE_SIZE +35MB. So: maximize per-wave ILP).
//   Phase A: QKV projection [256 tok x 192 n'], BK=64, 2-phase pipeline:
//            read frags -> barrier -> issue stage(kt+1) -> MFMA -> barrier(drains).
//   Epilogue: acc -> LDS Q-rows(R1) / K-rows / V^T, XOR bank-swizzled.
//   Phase B: flash attention from LDS; each wave owns groups {w, 15-w} (5 visits/wave),
//            DUAL-GROUP interleave per kt: QK(A)+QK(B), softmax(A)+(B) hides P-writes,
//            one lgkm drain, pf(A)+pf(B), PV(A) hides pf(B). setprio around MFMA.

typedef unsigned short u16;
typedef float f32x4 __attribute__((ext_vector_type(4)));
typedef short s16x8 __attribute__((ext_vector_type(8)));
typedef u16 u16x4 __attribute__((ext_vector_type(4)));

static constexpr int BB = 128;
static constexpr int TT = 256;
static constexpr int CC = 384;
static constexpr int HH = 6;
static constexpr int DD = 64;
static constexpr int MM = BB * TT;  // 32768

// ws layout (u16): WT3 [1152][384] | Xbf [M][384]
static constexpr size_t WTOFF = 0;
static constexpr size_t XOFF  = (size_t)3 * CC * CC;

// (1/sqrt(384)) * log2(e): folded into Wq so attn logits are already base-2
static constexpr float CSC = 0.07362242194579907f;

__device__ __forceinline__ u16 f2bf(float f) {
  unsigned u = __float_as_uint(f);
  u += 0x7fffu + ((u >> 16) & 1u);   // RTN-even
  return (u16)(u >> 16);
}

// async global->LDS, 16 B/lane; LDS dest = wave-uniform base + lane*16 (m104)
__device__ __forceinline__ void g2l16(const u16* g, u16* l) {
  __builtin_amdgcn_global_load_lds(
      (const __attribute__((address_space(1))) u16*)g,
      (__attribute__((address_space(3))) u16*)l, 16, 0, 0);
}

// ---------- prep: X fp32->bf16 (blocks 0..6143) + W^T via LDS transpose ----------
__global__ void prep(const float* __restrict__ X, const float* __restrict__ Wq,
                     const float* __restrict__ Wk, const float* __restrict__ Wv,
                     u16* __restrict__ ws) {
  int bx = blockIdx.x;
  if (bx < 6144) {
    size_t i = (size_t)(bx * 256 + threadIdx.x) * 8;
    f32x4 a0 = *(const f32x4*)(X + i);
    f32x4 a1 = *(const f32x4*)(X + i + 4);
    s16x8 ab;
#pragma unroll
    for (int j = 0; j < 4; ++j) { ab[j] = (short)f2bf(a0[j]); ab[4 + j] = (short)f2bf(a1[j]); }
    *(s16x8*)(ws + XOFF + i) = ab;
  } else {
    // 108 transpose blocks: z (3) x 6x6 tiles of 64x64
    __shared__ u16 Lt[64][66];
    int j = bx - 6144;
    int z = j / 36, t = j % 36, ti = t / 6, tj = t % 6;
    const float* W = (z == 0) ? Wq : (z == 1) ? Wk : Wv;
    const float sc = (z == 0) ? CSC : 1.0f;
    u16* WT = ws + WTOFF + (size_t)z * CC * CC;
    const int rl = threadIdx.x >> 4;
    const int cl = (threadIdx.x & 15) * 4;
#pragma unroll
    for (int it = 0; it < 4; ++it) {
      int r = it * 16 + rl;
      f32x4 v = *(const f32x4*)(W + (size_t)(ti * 64 + r) * CC + tj * 64 + cl);
#pragma unroll
      for (int q = 0; q < 4; ++q) Lt[r][cl + q] = f2bf(v[q] * sc);
    }
    __syncthreads();
#pragma unroll
    for (int it = 0; it < 4; ++it) {
      int n = it * 16 + rl;
      u16x4 o;
#pragma unroll
      for (int q = 0; q < 4; ++q) o[q] = Lt[cl + q][n];
      *(u16x4*)(WT + (size_t)(tj * 64 + n) * CC + ti * 64 + cl) = o;
    }
  }
}

// ---------- fused QKV projection + flash attention ----------
__global__ __launch_bounds__(512, 2) void fused(const u16* __restrict__ ws,
                                                float* __restrict__ out) {
  // XCD clustering: 6 heads of same b share ids congruent mod 8 -> same XCD L2
  const int bid = blockIdx.x;
  const int xc = bid & 7;
  const int g5 = bid >> 3;           // 0..95
  const int b = xc * 16 + g5 / 6;
  const int h = g5 % 6;

  __shared__ u16 R1[256][64];        // phase A: X chunk; phase B: Q rows (swizzled)
  __shared__ u16 R2[16384];          // phase A: W chunk (first 12288); phase B: Ps
  __shared__ u16 Ks[256][64];        // K rows, XOR-swizzled
  __shared__ u16 VTs[64][256];       // V^T, XOR-swizzled

  const int tid = threadIdx.x;
  const int lane = tid & 63;
  const int w = tid >> 6;            // 0..7
  const int quad = lane >> 4;
  const int col = lane & 15;

  const u16* Xg = ws + XOFF + (size_t)b * TT * CC;   // [256][384]
  const u16* Wg = ws + WTOFF;                        // [1152][384]
  u16* Wst = R2;                                     // [192][64] staging view

  const int rl = lane >> 3;          // row within 8-row staging chunk
  const int gb = (lane & 7) ^ rl;    // swizzled 8-elem block for this lane

  const int wm = (w >> 1) * 64;      // token quadrant
  const int wn = (w & 1) * 96;       // n' half (Q:0-63 K:64-127 V:128-191)

  auto stage = [&](int kt) {
#pragma unroll
    for (int i = 0; i < 4; ++i) {
      int r0 = w * 32 + i * 8;
      g2l16(Xg + (size_t)(r0 + rl) * CC + kt * 64 + gb * 8, &R1[r0][0]);
    }
#pragma unroll
    for (int i = 0; i < 3; ++i) {
      int r0 = w * 24 + i * 8;
      int rr = r0 + rl;
      int z = rr >> 6, nn = rr & 63;
      g2l16(Wg + (size_t)(z * CC + h * DD + nn) * CC + kt * 64 + gb * 8,
            Wst + r0 * 64);
    }
  };

  // ---------------- Phase A: 256x192 projection, BK=64, pipelined ----------------
  f32x4 acc[4][6] = {};

  stage(0);
  __syncthreads();                   // implicit vmcnt(0) drain + barrier

  for (int kt = 0; kt < 6; ++kt) {
    s16x8 af[4][2], bf[6][2];
#pragma unroll
    for (int mt = 0; mt < 4; ++mt)
#pragma unroll
      for (int ks = 0; ks < 2; ++ks)
        af[mt][ks] = *(const s16x8*)(&R1[wm + mt * 16 + col]
                                        [(((ks * 4 + quad) ^ (col & 7)) * 8)]);
#pragma unroll
    for (int nt = 0; nt < 6; ++nt)
#pragma unroll
      for (int ks = 0; ks < 2; ++ks)
        bf[nt][ks] = *(const s16x8*)(Wst + (wn + nt * 16 + col) * 64 +
                                     (((ks * 4 + quad) ^ (col & 7)) * 8));

    __syncthreads();                 // (a) all waves done reading this chunk
    if (kt < 5) stage(kt + 1);       // prefetch flies under the MFMAs

    __builtin_amdgcn_s_setprio(1);
#pragma unroll
    for (int ks = 0; ks < 2; ++ks)
#pragma unroll
      for (int mt = 0; mt < 4; ++mt)
#pragma unroll
        for (int nt = 0; nt < 6; ++nt)
          acc[mt][nt] = __builtin_amdgcn_mfma_f32_16x16x32_bf16(
              af[mt][ks], bf[nt][ks], acc[mt][nt], 0, 0, 0);
    __builtin_amdgcn_s_setprio(0);

    if (kt < 5) __syncthreads();     // (b) implicit vmcnt(0): staged chunk visible
  }
  // no barrier: (a) at kt=5 ordered all reads before epilogue writes

  // ---------------- Epilogue: acc -> Q(=R1)/K rows, V^T; XOR bank-swizzle ----------
#pragma unroll
  for (int mt = 0; mt < 4; ++mt) {
    int tokb = wm + mt * 16 + quad * 4;
#pragma unroll
    for (int nt = 0; nt < 6; ++nt) {
      int gn = wn + nt * 16 + col;           // class uniform per (w,nt)
      if (gn < 128) {
        u16* dst = (gn < 64) ? &R1[0][0] : &Ks[0][0];
        int d = gn & 63;
#pragma unroll
        for (int r = 0; r < 4; ++r) {
          int tok = tokb + r;
          dst[tok * 64 + (d ^ ((tok & 7) << 3))] = f2bf(acc[mt][nt][r]);
        }
      } else {
        int d = gn - 128;
        uint2 pk;
        pk.x = (unsigned)f2bf(acc[mt][nt][0]) | ((unsigned)f2bf(acc[mt][nt][1]) << 16);
        pk.y = (unsigned)f2bf(acc[mt][nt][2]) | ((unsigned)f2bf(acc[mt][nt][3]) << 16);
        *(uint2*)((u16*)VTs + d * 256 + (tokb ^ ((d & 15) << 3))) = pk;
      }
    }
  }
  __syncthreads();

  // ---------------- Phase B: flash attention from LDS, barrier-free ----------------
  const int g0 = w, g1 = 15 - w;             // this wave's two q-groups
  const int k0max = g0 >> 2, k1max = g1 >> 2;
  const int qq0 = (g0 & 3) * 16 + col;
  const int qq1 = (g1 & 3) * 16 + col;
  u16* PsA = R2 + w * 2048;                  // per-wave [16][64] swizzled
  u16* PsB = PsA + 1024;

  s16x8 qf[2][2];
  {
    int qr0 = g0 * 16 + col, qr1 = g1 * 16 + col;
#pragma unroll
    for (int ks = 0; ks < 2; ++ks) {
      qf[0][ks] = *(const s16x8*)(&R1[qr0][(((ks * 4 + quad) ^ (col & 7)) * 8)]);
      qf[1][ks] = *(const s16x8*)(&R1[qr1][(((ks * 4 + quad) ^ (col & 7)) * 8)]);
    }
  }

  f32x4 o[2][4] = {};
  float mst[2] = {-1.0e30f, -1.0e30f}, lst[2] = {0.0f, 0.0f};

  // softmax step: mask (if diag), row-max, rescale state, exp, pack to bf16 pairs
  auto sm = [&](f32x4 (&s)[4], bool diag, int qq, float& m, float& l,
                unsigned (&pk)[4][2]) -> float {
    float rmax = -1.0e30f;
#pragma unroll
    for (int nt = 0; nt < 4; ++nt)
#pragma unroll
      for (int r = 0; r < 4; ++r) {
        float t = s[nt][r];
        if (diag && (nt * 16 + quad * 4 + r) > qq) t = -1.0e30f;
        s[nt][r] = t;
        rmax = fmaxf(rmax, t);
      }
    rmax = fmaxf(rmax, __shfl_xor(rmax, 16));
    rmax = fmaxf(rmax, __shfl_xor(rmax, 32));
    float mn = fmaxf(m, rmax);
    float alpha = exp2f(m - mn);
    m = mn;
    float lsum = 0.0f;
#pragma unroll
    for (int nt = 0; nt < 4; ++nt) {
      float p0 = exp2f(s[nt][0] - mn), p1 = exp2f(s[nt][1] - mn);
      float p2 = exp2f(s[nt][2] - mn), p3 = exp2f(s[nt][3] - mn);
      lsum += (p0 + p1) + (p2 + p3);
      pk[nt][0] = (unsigned)f2bf(p0) | ((unsigned)f2bf(p1) << 16);
      pk[nt][1] = (unsigned)f2bf(p2) | ((unsigned)f2bf(p3) << 16);
    }
    l = l * alpha + lsum;
    return alpha;
  };

  for (int kt = 0; kt <= k1max; ++kt) {
    const bool both = (kt <= k0max);         // wave-uniform

    s16x8 kf[4][2], vf[4][2];
#pragma unroll
    for (int nt = 0; nt < 4; ++nt)
#pragma unroll
      for (int ks = 0; ks < 2; ++ks) {
        int key = kt * 64 + nt * 16 + col;
        kf[nt][ks] = *(const s16x8*)(&Ks[key][(((ks * 4 + quad) ^ (col & 7)) * 8)]);
        int d = nt * 16 + col;
        vf[nt][ks] = *(const s16x8*)((const u16*)VTs + d * 256 +
                     ((kt * 64 + ks * 32 + quad * 8) ^ ((d & 15) << 3)));
      }

    // QK^T both groups back-to-back (independent MFMA chains fill the pipe)
    f32x4 sA[4] = {}, sB[4] = {};
    __builtin_amdgcn_s_setprio(1);
    if (both) {
#pragma unroll
      for (int ks = 0; ks < 2; ++ks)
#pragma unroll
        for (int nt = 0; nt < 4; ++nt)
          sA[nt] = __builtin_amdgcn_mfma_f32_16x16x32_bf16(kf[nt][ks], qf[0][ks],
                                                           sA[nt], 0, 0, 0);
    }
#pragma unroll
    for (int ks = 0; ks < 2; ++ks)
#pragma unroll
      for (int nt = 0; nt < 4; ++nt)
        sB[nt] = __builtin_amdgcn_mfma_f32_16x16x32_bf16(kf[nt][ks], qf[1][ks],
                                                         sB[nt], 0, 0, 0);
    __builtin_amdgcn_s_setprio(0);

    unsigned pkA[4][2], pkB[4][2];
    float aA = 1.0f, aB;
    if (both) {
      aA = sm(sA, kt == k0max, qq0, mst[0], lst[0], pkA);
#pragma unroll
      for (int nt = 0; nt < 4; ++nt)
        *(uint2*)(PsA + col * 64 + ((nt * 16 + quad * 4) ^ ((col & 7) << 3))) =
            make_uint2(pkA[nt][0], pkA[nt][1]);
    }
    aB = sm(sB, kt == k1max, qq1, mst[1], lst[1], pkB);
#pragma unroll
    for (int nt = 0; nt < 4; ++nt)
      *(uint2*)(PsB + col * 64 + ((nt * 16 + quad * 4) ^ ((col & 7) << 3))) =
          make_uint2(pkB[nt][0], pkB[nt][1]);

    // O-rescales overlap the ds_write latency
    if (both) {
#pragma unroll
      for (int dt = 0; dt < 4; ++dt)
#pragma unroll
        for (int r = 0; r < 4; ++r) o[0][dt][r] *= aA;
    }
#pragma unroll
    for (int dt = 0; dt < 4; ++dt)
#pragma unroll
      for (int r = 0; r < 4; ++r) o[1][dt][r] *= aB;

    asm volatile("s_waitcnt lgkmcnt(0)" ::: "memory");  // P writes visible (own wave)

    s16x8 pfA[2], pfB[2];
    if (both) {
#pragma unroll
      for (int ks = 0; ks < 2; ++ks)
        pfA[ks] = *(const s16x8*)(PsA + col * 64 +
                                  ((ks * 32 + quad * 8) ^ ((col & 7) << 3)));
    }
#pragma unroll
    for (int ks = 0; ks < 2; ++ks)
      pfB[ks] = *(const s16x8*)(PsB + col * 64 +
                                ((ks * 32 + quad * 8) ^ ((col & 7) << 3)));

    __builtin_amdgcn_s_setprio(1);
    if (both) {
#pragma unroll
      for (int ks = 0; ks < 2; ++ks)
#pragma unroll
        for (int dt = 0; dt < 4; ++dt)
          o[0][dt] = __builtin_amdgcn_mfma_f32_16x16x32_bf16(vf[dt][ks], pfA[ks],
                                                             o[0][dt], 0, 0, 0);
    }
#pragma unroll
    for (int ks = 0; ks < 2; ++ks)
#pragma unroll
      for (int dt = 0; dt < 4; ++dt)
        o[1][dt] = __builtin_amdgcn_mfma_f32_16x16x32_bf16(vf[dt][ks], pfB[ks],
                                                           o[1][dt], 0, 0, 0);
    __builtin_amdgcn_s_setprio(0);
  }

  // epilogue: O^T row = d = dt*16+quad*4+r, col = q -> out[b,q,h*64+d]
#pragma unroll
  for (int gi = 0; gi < 2; ++gi) {
    int g = gi ? g1 : g0;
    float l = lst[gi];
    l += __shfl_xor(l, 16);
    l += __shfl_xor(l, 32);
    float inv = 1.0f / l;
    int q = g * 16 + col;
#pragma unroll
    for (int dt = 0; dt < 4; ++dt) {
      f32x4 res;
#pragma unroll
      for (int r = 0; r < 4; ++r) res[r] = o[gi][dt][r] * inv;
      *(f32x4*)(out + (size_t)(b * TT + q) * CC + h * DD + dt * 16 + quad * 4) = res;
    }
  }
}

extern "C" void kernel_launch(void* const* d_in, const int* in_sizes, int n_in,
                              void* d_out, int out_size, void* d_ws, size_t ws_size,
                              hipStream_t stream) {
  const float* x  = (const float*)d_in[0];
  const float* wq = (const float*)d_in[1];
  const float* wk = (const float*)d_in[2];
  const float* wv = (const float*)d_in[3];
  u16* ws  = (u16*)d_ws;
  float* out = (float*)d_out;

  prep<<<dim3(6144 + 108), 256, 0, stream>>>(x, wq, wk, wv, ws);
  fused<<<dim3(BB * HH), 512, 0, stream>>>(ws, out);
}

// Round 4
// 151.247 us; speedup vs baseline: 1.1054x; 1.0240x over previous
//
#include <hip/hip_runtime.h>

// Causal MHA, B=128 T=256 C=384 H=6 d=64, fp32 in/out.
// prep: X->bf16; W->W^T bf16 via LDS tile transpose (Wq pre-scaled by 1/sqrt(C)*log2e).
// fused: one block per (b,h), 512 thr = 8 waves, 1 block/CU (144KB LDS).
//   Phase A: QKV projection [256 tok x 192 n'], BK=64, DOUBLE-BUFFERED LDS with
//            counted vmcnt(7) waits (T3+T4): stage(kt+2) issued 2 phases ahead,
//            never drain vmcnt to 0 in steady state.
//   Epilogue: acc -> Q rows (X2[0]) / K rows (X2[1]) / V^T, XOR bank-swizzled,
//            packed via v_cvt_pk_bf16_f32.
//   Phase B: flash attention from LDS; waves own group pairs {w, 15-w} (5 visits);
//            dual-group interleave; defer-rescale THR=8 (T13); cvt_pk packs (T12).

typedef unsigned short u16;
typedef float f32x4 __attribute__((ext_vector_type(4)));
typedef short s16x8 __attribute__((ext_vector_type(8)));
typedef u16 u16x4 __attribute__((ext_vector_type(4)));

static constexpr int BB = 128;
static constexpr int TT = 256;
static constexpr int CC = 384;
static constexpr int HH = 6;
static constexpr int DD = 64;
static constexpr int MM = BB * TT;  // 32768

// ws layout (u16): WT3 [1152][384] | Xbf [M][384]
static constexpr size_t WTOFF = 0;
static constexpr size_t XOFF  = (size_t)3 * CC * CC;

// (1/sqrt(384)) * log2(e): folded into Wq so attn logits are already base-2
static constexpr float CSC = 0.07362242194579907f;

__device__ __forceinline__ u16 f2bf(float f) {
  unsigned u = __float_as_uint(f);
  u += 0x7fffu + ((u >> 16) & 1u);   // RTN-even
  return (u16)(u >> 16);
}

// packed f32 pair -> bf16 pair (RTN-even), single VALU op
__device__ __forceinline__ unsigned cvtpk(float lo, float hi) {
  unsigned r;
  asm("v_cvt_pk_bf16_f32 %0, %1, %2" : "=v"(r) : "v"(lo), "v"(hi));
  return r;
}

// async global->LDS, 16 B/lane; LDS dest = wave-uniform base + lane*16 (m104)
__device__ __forceinline__ void g2l16(const u16* g, u16* l) {
  __builtin_amdgcn_global_load_lds(
      (const __attribute__((address_space(1))) u16*)g,
      (__attribute__((address_space(3))) u16*)l, 16, 0, 0);
}

// ---------- prep: X fp32->bf16 (blocks 0..6143) + W^T via LDS transpose ----------
__global__ void prep(const float* __restrict__ X, const float* __restrict__ Wq,
                     const float* __restrict__ Wk, const float* __restrict__ Wv,
                     u16* __restrict__ ws) {
  int bx = blockIdx.x;
  if (bx < 6144) {
    size_t i = (size_t)(bx * 256 + threadIdx.x) * 8;
    f32x4 a0 = *(const f32x4*)(X + i);
    f32x4 a1 = *(const f32x4*)(X + i + 4);
    s16x8 ab;
#pragma unroll
    for (int j = 0; j < 4; ++j) { ab[j] = (short)f2bf(a0[j]); ab[4 + j] = (short)f2bf(a1[j]); }
    *(s16x8*)(ws + XOFF + i) = ab;
  } else {
    // 108 transpose blocks: z (3) x 6x6 tiles of 64x64
    __shared__ u16 Lt[64][66];
    int j = bx - 6144;
    int z = j / 36, t = j % 36, ti = t / 6, tj = t % 6;
    const float* W = (z == 0) ? Wq : (z == 1) ? Wk : Wv;
    const float sc = (z == 0) ? CSC : 1.0f;
    u16* WT = ws + WTOFF + (size_t)z * CC * CC;
    const int rl = threadIdx.x >> 4;
    const int cl = (threadIdx.x & 15) * 4;
#pragma unroll
    for (int it = 0; it < 4; ++it) {
      int r = it * 16 + rl;
      f32x4 v = *(const f32x4*)(W + (size_t)(ti * 64 + r) * CC + tj * 64 + cl);
#pragma unroll
      for (int q = 0; q < 4; ++q) Lt[r][cl + q] = f2bf(v[q] * sc);
    }
    __syncthreads();
#pragma unroll
    for (int it = 0; it < 4; ++it) {
      int n = it * 16 + rl;
      u16x4 o;
#pragma unroll
      for (int q = 0; q < 4; ++q) o[q] = Lt[cl + q][n];
      *(u16x4*)(WT + (size_t)(tj * 64 + n) * CC + ti * 64 + cl) = o;
    }
  }
}

// ---------- fused QKV projection + flash attention ----------
__global__ __launch_bounds__(512, 2) void fused(const u16* __restrict__ ws,
                                                float* __restrict__ out) {
  // XCD clustering: 6 heads of same b share ids congruent mod 8 -> same XCD L2
  const int bid = blockIdx.x;
  const int xc = bid & 7;
  const int g5 = bid >> 3;           // 0..95
  const int b = xc * 16 + g5 / 6;
  const int h = g5 % 6;

  __shared__ u16 X2[2][256][64];     // A: X dbuf; B: [0]=Q rows, [1]=K rows (swizzled)
  __shared__ u16 W2[2][192][64];     // A: W dbuf; B: Ps (16KB used)
  __shared__ u16 VTs[64][256];       // V^T, XOR-swizzled

  const int tid = threadIdx.x;
  const int lane = tid & 63;
  const int w = tid >> 6;            // 0..7
  const int quad = lane >> 4;
  const int col = lane & 15;

  const u16* Xg = ws + XOFF + (size_t)b * TT * CC;   // [256][384]
  const u16* Wg = ws + WTOFF;                        // [1152][384]

  const int rl = lane >> 3;          // row within 8-row staging chunk
  const int gb = (lane & 7) ^ rl;    // swizzled 8-elem block for this lane

  const int wm = (w >> 1) * 64;      // token quadrant
  const int wn = (w & 1) * 96;       // n' half (Q:0-63 K:64-127 V:128-191)

  auto stage = [&](int kt) {
    int bufi = kt & 1;
#pragma unroll
    for (int i = 0; i < 4; ++i) {
      int r0 = w * 32 + i * 8;
      g2l16(Xg + (size_t)(r0 + rl) * CC + kt * 64 + gb * 8, &X2[bufi][r0][0]);
    }
#pragma unroll
    for (int i = 0; i < 3; ++i) {
      int r0 = w * 24 + i * 8;
      int rr = r0 + rl;
      int z = rr >> 6, nn = rr & 63;
      g2l16(Wg + (size_t)(z * CC + h * DD + nn) * CC + kt * 64 + gb * 8,
            &W2[bufi][r0][0]);
    }
  };

  // ---------------- Phase A: 256x192 projection, 2-deep pipelined ----------------
  f32x4 acc[4][6] = {};

  stage(0);                          // 7 VMEM
  stage(1);                          // 7 VMEM (14 outstanding)

  for (int kt = 0; kt < 6; ++kt) {
    // counted wait: own stage(kt) loads done, stage(kt+1) stays in flight (T4)
    if (kt < 5) asm volatile("s_waitcnt vmcnt(7)" ::: "memory");
    else        asm volatile("s_waitcnt vmcnt(0)" ::: "memory");
    __builtin_amdgcn_s_barrier();    // all waves' stage(kt) complete
    __builtin_amdgcn_sched_barrier(0);

    const int bufi = kt & 1;
    s16x8 af[4][2], bf[6][2];
#pragma unroll
    for (int mt = 0; mt < 4; ++mt)
#pragma unroll
      for (int ks = 0; ks < 2; ++ks)
        af[mt][ks] = *(const s16x8*)(&X2[bufi][wm + mt * 16 + col]
                                        [(((ks * 4 + quad) ^ (col & 7)) * 8)]);
#pragma unroll
    for (int nt = 0; nt < 6; ++nt)
#pragma unroll
      for (int ks = 0; ks < 2; ++ks)
        bf[nt][ks] = *(const s16x8*)(&W2[bufi][wn + nt * 16 + col]
                                        [(((ks * 4 + quad) ^ (col & 7)) * 8)]);

    if (kt < 4) {
      asm volatile("s_waitcnt lgkmcnt(0)" ::: "memory");  // frag reads retired (WAR)
      __builtin_amdgcn_s_barrier();                       // all waves done reading buf
      __builtin_amdgcn_sched_barrier(0);
      stage(kt + 2);                                      // overwrite buf[kt&1]
    }

    __builtin_amdgcn_s_setprio(1);
#pragma unroll
    for (int ks = 0; ks < 2; ++ks)
#pragma unroll
      for (int mt = 0; mt < 4; ++mt)
#pragma unroll
        for (int nt = 0; nt < 6; ++nt)
          acc[mt][nt] = __builtin_amdgcn_mfma_f32_16x16x32_bf16(
              af[mt][ks], bf[nt][ks], acc[mt][nt], 0, 0, 0);
    __builtin_amdgcn_s_setprio(0);
  }

  __syncthreads();                   // all kt=5 reads retired before overlay writes

  // ------ Epilogue: acc -> Q(X2[0]) / K(X2[1]) rows, V^T; XOR bank-swizzle ------
  u16* Qb  = &X2[0][0][0];
  u16* KsB = &X2[1][0][0];
#pragma unroll
  for (int mt = 0; mt < 4; ++mt) {
    int tokb = wm + mt * 16 + quad * 4;
#pragma unroll
    for (int nt = 0; nt < 6; ++nt) {
      int gn = wn + nt * 16 + col;           // class uniform per (w,nt)
      unsigned u01 = cvtpk(acc[mt][nt][0], acc[mt][nt][1]);
      unsigned u23 = cvtpk(acc[mt][nt][2], acc[mt][nt][3]);
      if (gn < 128) {
        u16* dst = (gn < 64) ? Qb : KsB;
        int d = gn & 63;
        dst[(tokb + 0) * 64 + (d ^ (((tokb + 0) & 7) << 3))] = (u16)u01;
        dst[(tokb + 1) * 64 + (d ^ (((tokb + 1) & 7) << 3))] = (u16)(u01 >> 16);
        dst[(tokb + 2) * 64 + (d ^ (((tokb + 2) & 7) << 3))] = (u16)u23;
        dst[(tokb + 3) * 64 + (d ^ (((tokb + 3) & 7) << 3))] = (u16)(u23 >> 16);
      } else {
        int d = gn - 128;
        *(uint2*)((u16*)VTs + d * 256 + (tokb ^ ((d & 15) << 3))) =
            make_uint2(u01, u23);
      }
    }
  }
  __syncthreads();

  // ---------------- Phase B: flash attention from LDS, barrier-free ----------------
  const int g0 = w, g1 = 15 - w;             // this wave's two q-groups
  const int k0max = g0 >> 2, k1max = g1 >> 2;
  const int qq0 = (g0 & 3) * 16 + col;
  const int qq1 = (g1 & 3) * 16 + col;
  u16* PsA = (u16*)W2 + w * 2048;            // per-wave [16][64] swizzled
  u16* PsB = PsA + 1024;

  s16x8 qf[2][2];
  {
    int qr0 = g0 * 16 + col, qr1 = g1 * 16 + col;
#pragma unroll
    for (int ks = 0; ks < 2; ++ks) {
      qf[0][ks] = *(const s16x8*)(Qb + qr0 * 64 + (((ks * 4 + quad) ^ (col & 7)) * 8));
      qf[1][ks] = *(const s16x8*)(Qb + qr1 * 64 + (((ks * 4 + quad) ^ (col & 7)) * 8));
    }
  }

  f32x4 o[2][4] = {};
  float mst[2] = {-1.0e30f, -1.0e30f}, lst[2] = {0.0f, 0.0f};

  // softmax core: mask, tree row-max, defer-rescale (THR=8), exp2, cvt_pk pack.
  // Returns alpha; *deferred set wave-uniformly (skip O-rescale when true).
  auto sm = [&](f32x4 (&s)[4], bool diag, int qq, float& m, float& l,
                unsigned (&pk)[4][2], bool& deferred) -> float {
    float mx[4];
#pragma unroll
    for (int nt = 0; nt < 4; ++nt) {
      if (diag) {
#pragma unroll
        for (int r = 0; r < 4; ++r)
          if ((nt * 16 + quad * 4 + r) > qq) s[nt][r] = -1.0e30f;
      }
      mx[nt] = fmaxf(fmaxf(s[nt][0], s[nt][1]), fmaxf(s[nt][2], s[nt][3]));
    }
    float rmax = fmaxf(fmaxf(mx[0], mx[1]), fmaxf(mx[2], mx[3]));
    rmax = fmaxf(rmax, __shfl_xor(rmax, 16));
    rmax = fmaxf(rmax, __shfl_xor(rmax, 32));

    deferred = __all(rmax - m <= 8.0f);      // T13: P bounded by 2^8, keep old m
    float alpha = 1.0f;
    if (!deferred) {
      float mn = fmaxf(m, rmax);
      alpha = exp2f(m - mn);
      m = mn;
    }
    float lsum = 0.0f;
#pragma unroll
    for (int nt = 0; nt < 4; ++nt) {
      float p0 = exp2f(s[nt][0] - m), p1 = exp2f(s[nt][1] - m);
      float p2 = exp2f(s[nt][2] - m), p3 = exp2f(s[nt][3] - m);
      lsum += (p0 + p1) + (p2 + p3);
      pk[nt][0] = cvtpk(p0, p1);
      pk[nt][1] = cvtpk(p2, p3);
    }
    l = l * alpha + lsum;
    return alpha;
  };

  for (int kt = 0; kt <= k1max; ++kt) {
    const bool both = (kt <= k0max);         // wave-uniform

    s16x8 kf[4][2], vf[4][2];
#pragma unroll
    for (int nt = 0; nt < 4; ++nt)
#pragma unroll
      for (int ks = 0; ks < 2; ++ks) {
        int key = kt * 64 + nt * 16 + col;
        kf[nt][ks] = *(const s16x8*)(KsB + key * 64 +
                                     (((ks * 4 + quad) ^ (col & 7)) * 8));
        int d = nt * 16 + col;
        vf[nt][ks] = *(const s16x8*)((const u16*)VTs + d * 256 +
                     ((kt * 64 + ks * 32 + quad * 8) ^ ((d & 15) << 3)));
      }

    // QK^T both groups back-to-back (independent MFMA chains fill the pipe)
    f32x4 sA[4] = {}, sB[4] = {};
    __builtin_amdgcn_s_setprio(1);
    if (both) {
#pragma unroll
      for (int ks = 0; ks < 2; ++ks)
#pragma unroll
        for (int nt = 0; nt < 4; ++nt)
          sA[nt] = __builtin_amdgcn_mfma_f32_16x16x32_bf16(kf[nt][ks], qf[0][ks],
                                                           sA[nt], 0, 0, 0);
    }
#pragma unroll
    for (int ks = 0; ks < 2; ++ks)
#pragma unroll
      for (int nt = 0; nt < 4; ++nt)
        sB[nt] = __builtin_amdgcn_mfma_f32_16x16x32_bf16(kf[nt][ks], qf[1][ks],
                                                         sB[nt], 0, 0, 0);
    __builtin_amdgcn_s_setprio(0);

    unsigned pkA[4][2], pkB[4][2];
    bool dfA = true, dfB;
    float aA = 1.0f, aB;
    if (both) {
      aA = sm(sA, kt == k0max, qq0, mst[0], lst[0], pkA, dfA);
#pragma unroll
      for (int nt = 0; nt < 4; ++nt)
        *(uint2*)(PsA + col * 64 + ((nt * 16 + quad * 4) ^ ((col & 7) << 3))) =
            make_uint2(pkA[nt][0], pkA[nt][1]);
    }
    aB = sm(sB, kt == k1max, qq1, mst[1], lst[1], pkB, dfB);
#pragma unroll
    for (int nt = 0; nt < 4; ++nt)
      *(uint2*)(PsB + col * 64 + ((nt * 16 + quad * 4) ^ ((col & 7) << 3))) =
          make_uint2(pkB[nt][0], pkB[nt][1]);

    // O-rescales (skipped when deferred) overlap the ds_write latency
    if (both && !dfA) {
#pragma unroll
      for (int dt = 0; dt < 4; ++dt)
#pragma unroll
        for (int r = 0; r < 4; ++r) o[0][dt][r] *= aA;
    }
    if (!dfB) {
#pragma unroll
      for (int dt = 0; dt < 4; ++dt)
#pragma unroll
        for (int r = 0; r < 4; ++r) o[1][dt][r] *= aB;
    }

    asm volatile("s_waitcnt lgkmcnt(0)" ::: "memory");  // P writes visible (own wave)

    s16x8 pfA[2], pfB[2];
    if (both) {
#pragma unroll
      for (int ks = 0; ks < 2; ++ks)
        pfA[ks] = *(const s16x8*)(PsA + col * 64 +
                                  ((ks * 32 + quad * 8) ^ ((col & 7) << 3)));
    }
#pragma unroll
    for (int ks = 0; ks < 2; ++ks)
      pfB[ks] = *(const s16x8*)(PsB + col * 64 +
                                ((ks * 32 + quad * 8) ^ ((col & 7) << 3)));

    __builtin_amdgcn_s_setprio(1);
    if (both) {
#pragma unroll
      for (int ks = 0; ks < 2; ++ks)
#pragma unroll
        for (int dt = 0; dt < 4; ++dt)
          o[0][dt] = __builtin_amdgcn_mfma_f32_16x16x32_bf16(vf[dt][ks], pfA[ks],
                                                             o[0][dt], 0, 0, 0);
    }
#pragma unroll
    for (int ks = 0; ks < 2; ++ks)
#pragma unroll
      for (int dt = 0; dt < 4; ++dt)
        o[1][dt] = __builtin_amdgcn_mfma_f32_16x16x32_bf16(vf[dt][ks], pfB[ks],
                                                           o[1][dt], 0, 0, 0);
    __builtin_amdgcn_s_setprio(0);
  }

  // epilogue: O^T row = d = dt*16+quad*4+r, col = q -> out[b,q,h*64+d]
#pragma unroll
  for (int gi = 0; gi < 2; ++gi) {
    int g = gi ? g1 : g0;
    float l = lst[gi];
    l += __shfl_xor(l, 16);
    l += __shfl_xor(l, 32);
    float inv = 1.0f / l;
    int q = g * 16 + col;
#pragma unroll
    for (int dt = 0; dt < 4; ++dt) {
      f32x4 res;
#pragma unroll
      for (int r = 0; r < 4; ++r) res[r] = o[gi][dt][r] * inv;
      *(f32x4*)(out + (size_t)(b * TT + q) * CC + h * DD + dt * 16 + quad * 4) = res;
    }
  }
}

extern "C" void kernel_launch(void* const* d_in, const int* in_sizes, int n_in,
                              void* d_out, int out_size, void* d_ws, size_t ws_size,
                              hipStream_t stream) {
  const float* x  = (const float*)d_in[0];
  const float* wq = (const float*)d_in[1];
  const float* wk = (const float*)d_in[2];
  const float* wv = (const float*)d_in[3];
  u16* ws  = (u16*)d_ws;
  float* out = (float*)d_out;

  prep<<<dim3(6144 + 108), 256, 0, stream>>>(x, wq, wk, wv, ws);
  fused<<<dim3(BB * HH), 512, 0, stream>>>(ws, out);
}